// Round 5
// baseline (365.041 us; speedup 1.0000x reference)
//
#include <hip/hip_runtime.h>
#include <hip/hip_bf16.h>

// ---------------------------------------------------------------------------
// GCN graph classifier: 3x GCNConv(128->128) + ReLU, mean-pool(64), linear(10)
// Strategy:
//   * Build CSR (by dst) + sym-norm once per call (graph identical across layers)
//   * Per layer: agg = A_norm * x  (pull-based gather, wave per node),
//                x' = relu(agg @ W + b)  (fp32 tiled GEMM, vector ALU)
//   * Pool: batch sorted -> wave per 16-node chunk, float2/lane, atomic flush
//     at graph boundaries (R1: was 1 block/512 nodes -> 2% occupancy, 152us)
//   * Scan: 3-kernel parallel scan (R2: single-block was 137us @0.14% occ)
//   * Agg: edge loop unrolled x8 (R3 x4: 72->48us, FETCH const -> MLP-bound;
//     R4: deeper MLP)
//   * GEMM: LDS pitch 132 (R4: As[k][row] staging stores were 8-way bank
//     conflicted at pitch 128; 132 -> 4-way, float4-aligned)
//   * Final: (sums @ Wlin)/cnt + blin  -> out[64][10]
// ---------------------------------------------------------------------------

#define HID 128
#define NGRAPH 64

// runtime int32/int64 index accessor (reference declares int64; JAX default is
// int32 — detect on device and branch)
__device__ __forceinline__ int idx_at(const void* p, long long i, int f64) {
    if (f64) return (int)((const long long*)p)[i];
    return ((const int*)p)[i];
}

// Detect whether index arrays are int64: sample odd 32-bit words of edge_index;
// for little-endian int64 with values < 2^31 they are all zero.
__global__ void detect_kernel(const int* __restrict__ ei, int* __restrict__ flag) {
    __shared__ int cnt;
    if (threadIdx.x == 0) cnt = 0;
    __syncthreads();
    int z = 0;
    for (int i = threadIdx.x; i < 2048; i += 256)
        if (ei[2 * i + 1] == 0) z++;
    atomicAdd(&cnt, z);
    __syncthreads();
    if (threadIdx.x == 0) *flag = (cnt > 1024) ? 1 : 0;
}

__global__ void init_kernel(int* __restrict__ counts, float* __restrict__ pooled,
                            float* __restrict__ gcnt, int N) {
    int i = blockIdx.x * blockDim.x + threadIdx.x;
    if (i < N) counts[i] = 0;
    if (i < NGRAPH * HID) pooled[i] = 0.f;
    if (i < NGRAPH) gcnt[i] = 0.f;
}

__global__ void hist_kernel(const void* __restrict__ ei, const int* __restrict__ flag,
                            int* __restrict__ counts, int E, int N) {
    int e = blockIdx.x * blockDim.x + threadIdx.x;
    if (e >= E) return;
    int f64 = *flag;
    int d = idx_at(ei, (long long)E + e, f64);
    if ((unsigned)d < (unsigned)N) atomicAdd(&counts[d], 1);
}

__device__ __forceinline__ int wave_incl_scan(int v, int lane) {
#pragma unroll
    for (int off = 1; off < 64; off <<= 1) {
        int u = __shfl_up(v, off);
        if (lane >= off) v += u;
    }
    return v;
}

// ---- 3-kernel parallel exclusive scan over counts[N] (R2) ----
// A: per-block (256-elem) sums
__global__ __launch_bounds__(256) void blocksum_kernel(const int* __restrict__ counts,
                                                       int* __restrict__ bsums, int N) {
    int i = blockIdx.x * 256 + threadIdx.x;
    int v = (i < N) ? counts[i] : 0;
    int lane = threadIdx.x & 63, w = threadIdx.x >> 6;
#pragma unroll
    for (int off = 32; off > 0; off >>= 1) v += __shfl_down(v, off);
    __shared__ int ws[4];
    if (lane == 0) ws[w] = v;
    __syncthreads();
    if (threadIdx.x == 0) bsums[blockIdx.x] = ws[0] + ws[1] + ws[2] + ws[3];
}

// B: exclusive scan of the nb (<=256) block sums, in place
__global__ __launch_bounds__(256) void scanb_kernel(int* __restrict__ bsums, int nb) {
    int t = threadIdx.x;
    int lane = t & 63, w = t >> 6;
    int v = (t < nb) ? bsums[t] : 0;
    int iv = wave_incl_scan(v, lane);
    __shared__ int wsum[4];
    if (lane == 63) wsum[w] = iv;
    __syncthreads();
    int add = 0;
    for (int k = 0; k < w; ++k) add += wsum[k];
    if (t < nb) bsums[t] = iv - v + add;  // exclusive
}

// C: in-block exclusive scan + block offset -> rowstart/cursor/dinv
__global__ __launch_bounds__(256) void fill_kernel(const int* __restrict__ counts,
                                                   const int* __restrict__ bsums,
                                                   int* __restrict__ rowstart,
                                                   int* __restrict__ cursor,
                                                   float* __restrict__ dinv, int N) {
    int i = blockIdx.x * 256 + threadIdx.x;
    int c = (i < N) ? counts[i] : 0;
    int lane = threadIdx.x & 63, w = threadIdx.x >> 6;
    int iv = wave_incl_scan(c, lane);
    __shared__ int wsum[4];
    if (lane == 63) wsum[w] = iv;
    __syncthreads();
    int add = bsums[blockIdx.x];
    for (int k = 0; k < w; ++k) add += wsum[k];
    int excl = iv - c + add;
    if (i < N) {
        rowstart[i] = excl;
        cursor[i] = excl;
        dinv[i] = rsqrtf((float)(c + 1));
        if (i == N - 1) rowstart[N] = excl + c;
    }
}

__global__ void scatter_kernel(const void* __restrict__ ei, const int* __restrict__ flag,
                               int* __restrict__ cursor, const float* __restrict__ dinv,
                               int* __restrict__ csr_src, float* __restrict__ csr_norm,
                               int E, int N) {
    int e = blockIdx.x * blockDim.x + threadIdx.x;
    if (e >= E) return;
    int f64 = *flag;
    int s = idx_at(ei, e, f64);
    int d = idx_at(ei, (long long)E + e, f64);
    if ((unsigned)s >= (unsigned)N || (unsigned)d >= (unsigned)N) return;
    int pos = atomicAdd(&cursor[d], 1);
    csr_src[pos] = s;
    csr_norm[pos] = dinv[s] * dinv[d];
}

// out[i] = dinv[i]^2 * x[i] + sum_e norm_e * x[src_e]   (wave per node, float2/lane)
// R3/R4: edge loop unrolled (x4 -> x8): 8 independent 512B row-gathers in
// flight per wave; latency-bound regime (FETCH_SIZE constant across unroll).
__global__ __launch_bounds__(256) void agg_kernel(const float* __restrict__ x,
                                                  const int* __restrict__ rowstart,
                                                  const int* __restrict__ csr_src,
                                                  const float* __restrict__ csr_norm,
                                                  const float* __restrict__ dinv,
                                                  float* __restrict__ out, int N) {
    int wid = (blockIdx.x * blockDim.x + threadIdx.x) >> 6;
    int lane = threadIdx.x & 63;
    if (wid >= N) return;
    const float2* x2 = (const float2*)x;
    float di = dinv[wid];
    float w0 = di * di;
    float2 xs = x2[(size_t)wid * 64 + lane];
    float accx = w0 * xs.x, accy = w0 * xs.y;
    float bccx = 0.f, bccy = 0.f;
    int e0 = rowstart[wid], e1 = rowstart[wid + 1];
    int e = e0;
    for (; e + 8 <= e1; e += 8) {
        int s[8]; float wg[8]; float2 v[8];
#pragma unroll
        for (int u = 0; u < 8; ++u) s[u] = csr_src[e + u];
#pragma unroll
        for (int u = 0; u < 8; ++u) wg[u] = csr_norm[e + u];
#pragma unroll
        for (int u = 0; u < 8; ++u) v[u] = x2[(size_t)s[u] * 64 + lane];
#pragma unroll
        for (int u = 0; u < 8; u += 2) {
            accx = fmaf(wg[u], v[u].x, accx);
            accy = fmaf(wg[u], v[u].y, accy);
            bccx = fmaf(wg[u + 1], v[u + 1].x, bccx);
            bccy = fmaf(wg[u + 1], v[u + 1].y, bccy);
        }
    }
    for (; e + 4 <= e1; e += 4) {
        int s[4]; float wg[4]; float2 v[4];
#pragma unroll
        for (int u = 0; u < 4; ++u) s[u] = csr_src[e + u];
#pragma unroll
        for (int u = 0; u < 4; ++u) wg[u] = csr_norm[e + u];
#pragma unroll
        for (int u = 0; u < 4; ++u) v[u] = x2[(size_t)s[u] * 64 + lane];
#pragma unroll
        for (int u = 0; u < 4; u += 2) {
            accx = fmaf(wg[u], v[u].x, accx);
            accy = fmaf(wg[u], v[u].y, accy);
            bccx = fmaf(wg[u + 1], v[u + 1].x, bccx);
            bccy = fmaf(wg[u + 1], v[u + 1].y, bccy);
        }
    }
    for (; e < e1; ++e) {
        int s = csr_src[e];
        float w = csr_norm[e];
        float2 v = x2[(size_t)s * 64 + lane];
        accx = fmaf(w, v.x, accx);
        accy = fmaf(w, v.y, accy);
    }
    float2 r; r.x = accx + bccx; r.y = accy + bccy;
    ((float2*)out)[(size_t)wid * 64 + lane] = r;
}

// O = relu(A @ W + bias), A:[M][128], W:[128][128]. 128x128 tile, 8x8 microtile.
// R4: LDS pitch 132 — pitch-128 As[k][row] scalar staging stores hit bank =
// row%32 with 8 distinct rows/wave = 8-way conflict; 132 spreads to 16 banks.
#define LP 132
__global__ __launch_bounds__(256) void gemm_bias_relu(const float* __restrict__ A,
                                                      const float* __restrict__ W,
                                                      const float* __restrict__ bias,
                                                      float* __restrict__ O, int M) {
    __shared__ float As[32][LP];  // As[k][r] (transposed)
    __shared__ float Ws[32][LP];  // Ws[k][c]
    int t = threadIdx.x;
    int tx = t & 15, ty = t >> 4;
    int r0 = ty * 8, c0 = tx * 8;
    int blockRow = blockIdx.x * 128;
    float acc[8][8];
#pragma unroll
    for (int i = 0; i < 8; i++)
#pragma unroll
        for (int j = 0; j < 8; j++) acc[i][j] = 0.f;

    for (int k0 = 0; k0 < 128; k0 += 32) {
        __syncthreads();
        // stage A chunk (transpose): id = t + 256q; row=id>>3, kk4=id&7
#pragma unroll
        for (int q = 0; q < 4; ++q) {
            int id = t + 256 * q;
            int row = id >> 3, kk4 = id & 7;
            int grow = blockRow + row;
            float4 v = make_float4(0.f, 0.f, 0.f, 0.f);
            if (grow < M) v = *(const float4*)&A[(size_t)grow * 128 + k0 + kk4 * 4];
            As[kk4 * 4 + 0][row] = v.x;
            As[kk4 * 4 + 1][row] = v.y;
            As[kk4 * 4 + 2][row] = v.z;
            As[kk4 * 4 + 3][row] = v.w;
        }
        // stage W chunk: id = t + 256q; krow=id>>5, c4=id&31
#pragma unroll
        for (int q = 0; q < 4; ++q) {
            int id = t + 256 * q;
            int krow = id >> 5, c4 = id & 31;
            float4 v = *(const float4*)&W[(size_t)(k0 + krow) * 128 + c4 * 4];
            *(float4*)&Ws[krow][c4 * 4] = v;
        }
        __syncthreads();
#pragma unroll 4
        for (int k = 0; k < 32; ++k) {
            float4 a0 = *(const float4*)&As[k][r0];
            float4 a1 = *(const float4*)&As[k][r0 + 4];
            float4 b0 = *(const float4*)&Ws[k][c0];
            float4 b1 = *(const float4*)&Ws[k][c0 + 4];
            float a[8] = {a0.x, a0.y, a0.z, a0.w, a1.x, a1.y, a1.z, a1.w};
            float b[8] = {b0.x, b0.y, b0.z, b0.w, b1.x, b1.y, b1.z, b1.w};
#pragma unroll
            for (int i = 0; i < 8; i++)
#pragma unroll
                for (int j = 0; j < 8; j++) acc[i][j] = fmaf(a[i], b[j], acc[i][j]);
        }
    }
#pragma unroll
    for (int i = 0; i < 8; i++) {
        int gr = blockRow + r0 + i;
        if (gr >= M) break;
#pragma unroll
        for (int j = 0; j < 8; j += 4) {
            float4 o;
            o.x = fmaxf(acc[i][j + 0] + bias[c0 + j + 0], 0.f);
            o.y = fmaxf(acc[i][j + 1] + bias[c0 + j + 1], 0.f);
            o.z = fmaxf(acc[i][j + 2] + bias[c0 + j + 2], 0.f);
            o.w = fmaxf(acc[i][j + 3] + bias[c0 + j + 3], 0.f);
            *(float4*)&O[(size_t)gr * 128 + c0 + j] = o;
        }
    }
}

// batch is sorted: one WAVE per 16-node chunk, float2 per lane (128 features),
// running per-graph accumulation in registers, atomic flush at graph
// boundaries. R1 rewrite: was 1 block per 512 nodes -> 2% occupancy, 152us.
#define POOL_CHUNK 16
__global__ __launch_bounds__(256) void pool_kernel(const float* __restrict__ h,
                                                   const void* __restrict__ batch,
                                                   const int* __restrict__ flag,
                                                   float* __restrict__ pooled,
                                                   float* __restrict__ gcnt, int N) {
    int wid = (blockIdx.x * blockDim.x + threadIdx.x) >> 6;
    int lane = threadIdx.x & 63;
    int n0 = wid * POOL_CHUNK;
    if (n0 >= N) return;
    int n1 = n0 + POOL_CHUNK; if (n1 > N) n1 = N;
    int f64 = *flag;
    const float2* h2 = (const float2*)h;
    int g = idx_at(batch, n0, f64);
    float ax = 0.f, ay = 0.f;
    int cnt = 0;
    for (int n = n0; n < n1; ++n) {
        int gn = idx_at(batch, n, f64);
        if (gn != g) {
            if ((unsigned)g < (unsigned)NGRAPH) {
                atomicAdd(&pooled[g * HID + 2 * lane], ax);
                atomicAdd(&pooled[g * HID + 2 * lane + 1], ay);
                if (lane == 0) atomicAdd(&gcnt[g], (float)cnt);
            }
            ax = ay = 0.f; cnt = 0; g = gn;
        }
        float2 v = h2[(size_t)n * 64 + lane];
        ax += v.x; ay += v.y; cnt++;
    }
    if ((unsigned)g < (unsigned)NGRAPH) {
        atomicAdd(&pooled[g * HID + 2 * lane], ax);
        atomicAdd(&pooled[g * HID + 2 * lane + 1], ay);
        if (lane == 0) atomicAdd(&gcnt[g], (float)cnt);
    }
}

__global__ __launch_bounds__(128) void final_kernel(const float* __restrict__ pooled,
                                                    const float* __restrict__ gcnt,
                                                    const float* __restrict__ Wl,
                                                    const float* __restrict__ bl,
                                                    float* __restrict__ out) {
    int o = blockIdx.x * blockDim.x + threadIdx.x;
    if (o >= NGRAPH * 10) return;
    int g = o / 10, c = o % 10;
    float inv = 1.0f / fmaxf(gcnt[g], 1.0f);
    float acc = 0.f;
    for (int k = 0; k < HID; ++k)
        acc = fmaf(pooled[g * HID + k], Wl[k * 10 + c], acc);
    out[o] = acc * inv + bl[c];
}

extern "C" void kernel_launch(void* const* d_in, const int* in_sizes, int n_in,
                              void* d_out, int out_size, void* d_ws, size_t ws_size,
                              hipStream_t stream) {
    const float* x   = (const float*)d_in[0];
    const void* ei   = d_in[1];
    const void* bat  = d_in[2];
    const float* W1  = (const float*)d_in[3];
    const float* b1  = (const float*)d_in[4];
    const float* W2  = (const float*)d_in[5];
    const float* b2  = (const float*)d_in[6];
    const float* W3  = (const float*)d_in[7];
    const float* b3  = (const float*)d_in[8];
    const float* Wl  = (const float*)d_in[9];
    const float* bl  = (const float*)d_in[10];
    float* out = (float*)d_out;

    const int N = in_sizes[0] / HID;   // 50000
    const int E = in_sizes[1] / 2;     // 600000

    char* w = (char*)d_ws;
    size_t off = 0;
    auto carve = [&](size_t bytes) -> void* {
        void* p = w + off;
        off = (off + bytes + 255) & ~(size_t)255;
        return p;
    };
    float* bufA     = (float*)carve((size_t)N * HID * 4);
    float* bufB     = (float*)carve((size_t)N * HID * 4);
    int*   counts   = (int*)carve((size_t)N * 4);
    int*   rowstart = (int*)carve((size_t)(N + 1) * 4);
    int*   cursor   = (int*)carve((size_t)N * 4);
    float* dinv     = (float*)carve((size_t)N * 4);
    int*   csr_src  = (int*)carve((size_t)E * 4);
    float* csr_norm = (float*)carve((size_t)E * 4);
    float* pooled   = (float*)carve((size_t)NGRAPH * HID * 4);
    float* gcnt     = (float*)carve((size_t)NGRAPH * 4);
    int*   bsums    = (int*)carve(1024);
    int*   flag     = (int*)carve(256);

    const int nb = (N + 255) / 256;  // scan blocks (196 for N=50000)

    // graph preprocessing (once; shared by all 3 layers)
    detect_kernel<<<1, 256, 0, stream>>>((const int*)ei, flag);
    init_kernel<<<(N + 255) / 256, 256, 0, stream>>>(counts, pooled, gcnt, N);
    hist_kernel<<<(E + 255) / 256, 256, 0, stream>>>(ei, flag, counts, E, N);
    blocksum_kernel<<<nb, 256, 0, stream>>>(counts, bsums, N);
    scanb_kernel<<<1, 256, 0, stream>>>(bsums, nb);
    fill_kernel<<<nb, 256, 0, stream>>>(counts, bsums, rowstart, cursor, dinv, N);
    scatter_kernel<<<(E + 255) / 256, 256, 0, stream>>>(ei, flag, cursor, dinv,
                                                        csr_src, csr_norm, E, N);

    int aggBlocks  = (N + 3) / 4;          // one wave per node, 4 waves/block
    int gemmBlocks = (N + 127) / 128;

    // layer 1: agg(x)->B, relu(B@W1+b1)->A
    agg_kernel<<<aggBlocks, 256, 0, stream>>>(x, rowstart, csr_src, csr_norm, dinv, bufB, N);
    gemm_bias_relu<<<gemmBlocks, 256, 0, stream>>>(bufB, W1, b1, bufA, N);
    // layer 2
    agg_kernel<<<aggBlocks, 256, 0, stream>>>(bufA, rowstart, csr_src, csr_norm, dinv, bufB, N);
    gemm_bias_relu<<<gemmBlocks, 256, 0, stream>>>(bufB, W2, b2, bufA, N);
    // layer 3
    agg_kernel<<<aggBlocks, 256, 0, stream>>>(bufA, rowstart, csr_src, csr_norm, dinv, bufB, N);
    gemm_bias_relu<<<gemmBlocks, 256, 0, stream>>>(bufB, W3, b3, bufA, N);

    // mean pool + final linear
    int poolWaves = (N + POOL_CHUNK - 1) / POOL_CHUNK;
    int poolBlocks = (poolWaves + 3) / 4;
    pool_kernel<<<poolBlocks, 256, 0, stream>>>(bufA, bat, flag, pooled, gcnt, N);
    final_kernel<<<5, 128, 0, stream>>>(pooled, gcnt, Wl, bl, out);
}

// Round 6
// 355.172 us; speedup vs baseline: 1.0278x; 1.0278x over previous
//
#include <hip/hip_runtime.h>
#include <hip/hip_bf16.h>

// ---------------------------------------------------------------------------
// GCN graph classifier: 3x GCNConv(128->128) + ReLU, mean-pool(64), linear(10)
// Strategy:
//   * Build CSR (by dst) once per call (graph identical across layers)
//   * Per layer: agg = A_norm * x  (pull-based gather, wave per node),
//                x' = relu(agg @ W + b)  (fp32 tiled GEMM, vector ALU)
//   * Pool: batch sorted -> wave per 16-node chunk, float2/lane, atomic flush
//     at graph boundaries (R1: was 1 block/512 nodes -> 2% occupancy, 152us)
//   * Scan: 3-kernel parallel scan (R2: single-block was 137us @0.14% occ)
//   * Agg: edge loop unrolled x8 (R3: MLP 1->4 = 72->48us; R4: 4->8 neutral ->
//     plateau); norm computed on the fly from dinv (R5)
//   * Scatter: stores ONLY csr_src (R5: csr_norm store removed -- WRITE_SIZE
//     was 67MB of write-allocate amplification from 2 random 4B stores/edge;
//     norm = dinv[s]*dinv[d] recomputed in agg where dinv[d] is in-register)
//   * GEMM: LDS pitch 132 (R4: neutral, kept)
//   * Final: (sums @ Wlin)/cnt + blin  -> out[64][10]
// ---------------------------------------------------------------------------

#define HID 128
#define NGRAPH 64

// runtime int32/int64 index accessor (reference declares int64; JAX default is
// int32 — detect on device and branch)
__device__ __forceinline__ int idx_at(const void* p, long long i, int f64) {
    if (f64) return (int)((const long long*)p)[i];
    return ((const int*)p)[i];
}

// Detect whether index arrays are int64: sample odd 32-bit words of edge_index;
// for little-endian int64 with values < 2^31 they are all zero.
__global__ void detect_kernel(const int* __restrict__ ei, int* __restrict__ flag) {
    __shared__ int cnt;
    if (threadIdx.x == 0) cnt = 0;
    __syncthreads();
    int z = 0;
    for (int i = threadIdx.x; i < 2048; i += 256)
        if (ei[2 * i + 1] == 0) z++;
    atomicAdd(&cnt, z);
    __syncthreads();
    if (threadIdx.x == 0) *flag = (cnt > 1024) ? 1 : 0;
}

__global__ void init_kernel(int* __restrict__ counts, float* __restrict__ pooled,
                            float* __restrict__ gcnt, int N) {
    int i = blockIdx.x * blockDim.x + threadIdx.x;
    if (i < N) counts[i] = 0;
    if (i < NGRAPH * HID) pooled[i] = 0.f;
    if (i < NGRAPH) gcnt[i] = 0.f;
}

__global__ void hist_kernel(const void* __restrict__ ei, const int* __restrict__ flag,
                            int* __restrict__ counts, int E, int N) {
    int e = blockIdx.x * blockDim.x + threadIdx.x;
    if (e >= E) return;
    int f64 = *flag;
    int d = idx_at(ei, (long long)E + e, f64);
    if ((unsigned)d < (unsigned)N) atomicAdd(&counts[d], 1);
}

__device__ __forceinline__ int wave_incl_scan(int v, int lane) {
#pragma unroll
    for (int off = 1; off < 64; off <<= 1) {
        int u = __shfl_up(v, off);
        if (lane >= off) v += u;
    }
    return v;
}

// ---- 3-kernel parallel exclusive scan over counts[N] (R2) ----
// A: per-block (256-elem) sums
__global__ __launch_bounds__(256) void blocksum_kernel(const int* __restrict__ counts,
                                                       int* __restrict__ bsums, int N) {
    int i = blockIdx.x * 256 + threadIdx.x;
    int v = (i < N) ? counts[i] : 0;
    int lane = threadIdx.x & 63, w = threadIdx.x >> 6;
#pragma unroll
    for (int off = 32; off > 0; off >>= 1) v += __shfl_down(v, off);
    __shared__ int ws[4];
    if (lane == 0) ws[w] = v;
    __syncthreads();
    if (threadIdx.x == 0) bsums[blockIdx.x] = ws[0] + ws[1] + ws[2] + ws[3];
}

// B: exclusive scan of the nb (<=256) block sums, in place
__global__ __launch_bounds__(256) void scanb_kernel(int* __restrict__ bsums, int nb) {
    int t = threadIdx.x;
    int lane = t & 63, w = t >> 6;
    int v = (t < nb) ? bsums[t] : 0;
    int iv = wave_incl_scan(v, lane);
    __shared__ int wsum[4];
    if (lane == 63) wsum[w] = iv;
    __syncthreads();
    int add = 0;
    for (int k = 0; k < w; ++k) add += wsum[k];
    if (t < nb) bsums[t] = iv - v + add;  // exclusive
}

// C: in-block exclusive scan + block offset -> rowstart/cursor/dinv
__global__ __launch_bounds__(256) void fill_kernel(const int* __restrict__ counts,
                                                   const int* __restrict__ bsums,
                                                   int* __restrict__ rowstart,
                                                   int* __restrict__ cursor,
                                                   float* __restrict__ dinv, int N) {
    int i = blockIdx.x * 256 + threadIdx.x;
    int c = (i < N) ? counts[i] : 0;
    int lane = threadIdx.x & 63, w = threadIdx.x >> 6;
    int iv = wave_incl_scan(c, lane);
    __shared__ int wsum[4];
    if (lane == 63) wsum[w] = iv;
    __syncthreads();
    int add = bsums[blockIdx.x];
    for (int k = 0; k < w; ++k) add += wsum[k];
    int excl = iv - c + add;
    if (i < N) {
        rowstart[i] = excl;
        cursor[i] = excl;
        dinv[i] = rsqrtf((float)(c + 1));
        if (i == N - 1) rowstart[N] = excl + c;
    }
}

// R5: stores ONLY csr_src (norm recomputed in agg) -> halves random write-
// allocate traffic (was 67MB WRITE_SIZE), drops dinv gather reads here.
__global__ void scatter_kernel(const void* __restrict__ ei, const int* __restrict__ flag,
                               int* __restrict__ cursor,
                               int* __restrict__ csr_src, int E, int N) {
    int e = blockIdx.x * blockDim.x + threadIdx.x;
    if (e >= E) return;
    int f64 = *flag;
    int s = idx_at(ei, e, f64);
    int d = idx_at(ei, (long long)E + e, f64);
    if ((unsigned)s >= (unsigned)N || (unsigned)d >= (unsigned)N) return;
    int pos = atomicAdd(&cursor[d], 1);
    csr_src[pos] = s;
}

// out[i] = dinv[i]^2 * x[i] + sum_e (dinv[s]*dinv[i]) * x[s]
// (wave per node, float2/lane). R3/R4: edge loop unrolled x8 for MLP.
// R5: per-edge weight = dinv[s]*di computed on the fly (dinv is 200KB,
// L2-resident, wave-uniform broadcast loads batched with the row gathers).
__global__ __launch_bounds__(256) void agg_kernel(const float* __restrict__ x,
                                                  const int* __restrict__ rowstart,
                                                  const int* __restrict__ csr_src,
                                                  const float* __restrict__ dinv,
                                                  float* __restrict__ out, int N) {
    int wid = (blockIdx.x * blockDim.x + threadIdx.x) >> 6;
    int lane = threadIdx.x & 63;
    if (wid >= N) return;
    const float2* x2 = (const float2*)x;
    float di = dinv[wid];
    float w0 = di * di;
    float2 xs = x2[(size_t)wid * 64 + lane];
    float accx = w0 * xs.x, accy = w0 * xs.y;
    float bccx = 0.f, bccy = 0.f;
    int e0 = rowstart[wid], e1 = rowstart[wid + 1];
    int e = e0;
    for (; e + 8 <= e1; e += 8) {
        int s[8]; float ds[8]; float2 v[8];
#pragma unroll
        for (int u = 0; u < 8; ++u) s[u] = csr_src[e + u];
#pragma unroll
        for (int u = 0; u < 8; ++u) ds[u] = dinv[s[u]];
#pragma unroll
        for (int u = 0; u < 8; ++u) v[u] = x2[(size_t)s[u] * 64 + lane];
#pragma unroll
        for (int u = 0; u < 8; u += 2) {
            float wa = ds[u] * di, wb = ds[u + 1] * di;
            accx = fmaf(wa, v[u].x, accx);
            accy = fmaf(wa, v[u].y, accy);
            bccx = fmaf(wb, v[u + 1].x, bccx);
            bccy = fmaf(wb, v[u + 1].y, bccy);
        }
    }
    for (; e + 4 <= e1; e += 4) {
        int s[4]; float ds[4]; float2 v[4];
#pragma unroll
        for (int u = 0; u < 4; ++u) s[u] = csr_src[e + u];
#pragma unroll
        for (int u = 0; u < 4; ++u) ds[u] = dinv[s[u]];
#pragma unroll
        for (int u = 0; u < 4; ++u) v[u] = x2[(size_t)s[u] * 64 + lane];
#pragma unroll
        for (int u = 0; u < 4; u += 2) {
            float wa = ds[u] * di, wb = ds[u + 1] * di;
            accx = fmaf(wa, v[u].x, accx);
            accy = fmaf(wa, v[u].y, accy);
            bccx = fmaf(wb, v[u + 1].x, bccx);
            bccy = fmaf(wb, v[u + 1].y, bccy);
        }
    }
    for (; e < e1; ++e) {
        int s = csr_src[e];
        float w = dinv[s] * di;
        float2 v = x2[(size_t)s * 64 + lane];
        accx = fmaf(w, v.x, accx);
        accy = fmaf(w, v.y, accy);
    }
    float2 r; r.x = accx + bccx; r.y = accy + bccy;
    ((float2*)out)[(size_t)wid * 64 + lane] = r;
}

// O = relu(A @ W + bias), A:[M][128], W:[128][128]. 128x128 tile, 8x8 microtile.
// R4: LDS pitch 132 (staging-store bank spread; measured neutral, kept).
#define LP 132
__global__ __launch_bounds__(256) void gemm_bias_relu(const float* __restrict__ A,
                                                      const float* __restrict__ W,
                                                      const float* __restrict__ bias,
                                                      float* __restrict__ O, int M) {
    __shared__ float As[32][LP];  // As[k][r] (transposed)
    __shared__ float Ws[32][LP];  // Ws[k][c]
    int t = threadIdx.x;
    int tx = t & 15, ty = t >> 4;
    int r0 = ty * 8, c0 = tx * 8;
    int blockRow = blockIdx.x * 128;
    float acc[8][8];
#pragma unroll
    for (int i = 0; i < 8; i++)
#pragma unroll
        for (int j = 0; j < 8; j++) acc[i][j] = 0.f;

    for (int k0 = 0; k0 < 128; k0 += 32) {
        __syncthreads();
        // stage A chunk (transpose): id = t + 256q; row=id>>3, kk4=id&7
#pragma unroll
        for (int q = 0; q < 4; ++q) {
            int id = t + 256 * q;
            int row = id >> 3, kk4 = id & 7;
            int grow = blockRow + row;
            float4 v = make_float4(0.f, 0.f, 0.f, 0.f);
            if (grow < M) v = *(const float4*)&A[(size_t)grow * 128 + k0 + kk4 * 4];
            As[kk4 * 4 + 0][row] = v.x;
            As[kk4 * 4 + 1][row] = v.y;
            As[kk4 * 4 + 2][row] = v.z;
            As[kk4 * 4 + 3][row] = v.w;
        }
        // stage W chunk: id = t + 256q; krow=id>>5, c4=id&31
#pragma unroll
        for (int q = 0; q < 4; ++q) {
            int id = t + 256 * q;
            int krow = id >> 5, c4 = id & 31;
            float4 v = *(const float4*)&W[(size_t)(k0 + krow) * 128 + c4 * 4];
            *(float4*)&Ws[krow][c4 * 4] = v;
        }
        __syncthreads();
#pragma unroll 4
        for (int k = 0; k < 32; ++k) {
            float4 a0 = *(const float4*)&As[k][r0];
            float4 a1 = *(const float4*)&As[k][r0 + 4];
            float4 b0 = *(const float4*)&Ws[k][c0];
            float4 b1 = *(const float4*)&Ws[k][c0 + 4];
            float a[8] = {a0.x, a0.y, a0.z, a0.w, a1.x, a1.y, a1.z, a1.w};
            float b[8] = {b0.x, b0.y, b0.z, b0.w, b1.x, b1.y, b1.z, b1.w};
#pragma unroll
            for (int i = 0; i < 8; i++)
#pragma unroll
                for (int j = 0; j < 8; j++) acc[i][j] = fmaf(a[i], b[j], acc[i][j]);
        }
    }
#pragma unroll
    for (int i = 0; i < 8; i++) {
        int gr = blockRow + r0 + i;
        if (gr >= M) break;
#pragma unroll
        for (int j = 0; j < 8; j += 4) {
            float4 o;
            o.x = fmaxf(acc[i][j + 0] + bias[c0 + j + 0], 0.f);
            o.y = fmaxf(acc[i][j + 1] + bias[c0 + j + 1], 0.f);
            o.z = fmaxf(acc[i][j + 2] + bias[c0 + j + 2], 0.f);
            o.w = fmaxf(acc[i][j + 3] + bias[c0 + j + 3], 0.f);
            *(float4*)&O[(size_t)gr * 128 + c0 + j] = o;
        }
    }
}

// batch is sorted: one WAVE per 16-node chunk, float2 per lane (128 features),
// running per-graph accumulation in registers, atomic flush at graph
// boundaries. R1 rewrite: was 1 block per 512 nodes -> 2% occupancy, 152us.
#define POOL_CHUNK 16
__global__ __launch_bounds__(256) void pool_kernel(const float* __restrict__ h,
                                                   const void* __restrict__ batch,
                                                   const int* __restrict__ flag,
                                                   float* __restrict__ pooled,
                                                   float* __restrict__ gcnt, int N) {
    int wid = (blockIdx.x * blockDim.x + threadIdx.x) >> 6;
    int lane = threadIdx.x & 63;
    int n0 = wid * POOL_CHUNK;
    if (n0 >= N) return;
    int n1 = n0 + POOL_CHUNK; if (n1 > N) n1 = N;
    int f64 = *flag;
    const float2* h2 = (const float2*)h;
    int g = idx_at(batch, n0, f64);
    float ax = 0.f, ay = 0.f;
    int cnt = 0;
    for (int n = n0; n < n1; ++n) {
        int gn = idx_at(batch, n, f64);
        if (gn != g) {
            if ((unsigned)g < (unsigned)NGRAPH) {
                atomicAdd(&pooled[g * HID + 2 * lane], ax);
                atomicAdd(&pooled[g * HID + 2 * lane + 1], ay);
                if (lane == 0) atomicAdd(&gcnt[g], (float)cnt);
            }
            ax = ay = 0.f; cnt = 0; g = gn;
        }
        float2 v = h2[(size_t)n * 64 + lane];
        ax += v.x; ay += v.y; cnt++;
    }
    if ((unsigned)g < (unsigned)NGRAPH) {
        atomicAdd(&pooled[g * HID + 2 * lane], ax);
        atomicAdd(&pooled[g * HID + 2 * lane + 1], ay);
        if (lane == 0) atomicAdd(&gcnt[g], (float)cnt);
    }
}

__global__ __launch_bounds__(128) void final_kernel(const float* __restrict__ pooled,
                                                    const float* __restrict__ gcnt,
                                                    const float* __restrict__ Wl,
                                                    const float* __restrict__ bl,
                                                    float* __restrict__ out) {
    int o = blockIdx.x * blockDim.x + threadIdx.x;
    if (o >= NGRAPH * 10) return;
    int g = o / 10, c = o % 10;
    float inv = 1.0f / fmaxf(gcnt[g], 1.0f);
    float acc = 0.f;
    for (int k = 0; k < HID; ++k)
        acc = fmaf(pooled[g * HID + k], Wl[k * 10 + c], acc);
    out[o] = acc * inv + bl[c];
}

extern "C" void kernel_launch(void* const* d_in, const int* in_sizes, int n_in,
                              void* d_out, int out_size, void* d_ws, size_t ws_size,
                              hipStream_t stream) {
    const float* x   = (const float*)d_in[0];
    const void* ei   = d_in[1];
    const void* bat  = d_in[2];
    const float* W1  = (const float*)d_in[3];
    const float* b1  = (const float*)d_in[4];
    const float* W2  = (const float*)d_in[5];
    const float* b2  = (const float*)d_in[6];
    const float* W3  = (const float*)d_in[7];
    const float* b3  = (const float*)d_in[8];
    const float* Wl  = (const float*)d_in[9];
    const float* bl  = (const float*)d_in[10];
    float* out = (float*)d_out;

    const int N = in_sizes[0] / HID;   // 50000
    const int E = in_sizes[1] / 2;     // 600000

    char* w = (char*)d_ws;
    size_t off = 0;
    auto carve = [&](size_t bytes) -> void* {
        void* p = w + off;
        off = (off + bytes + 255) & ~(size_t)255;
        return p;
    };
    float* bufA     = (float*)carve((size_t)N * HID * 4);
    float* bufB     = (float*)carve((size_t)N * HID * 4);
    int*   counts   = (int*)carve((size_t)N * 4);
    int*   rowstart = (int*)carve((size_t)(N + 1) * 4);
    int*   cursor   = (int*)carve((size_t)N * 4);
    float* dinv     = (float*)carve((size_t)N * 4);
    int*   csr_src  = (int*)carve((size_t)E * 4);
    float* pooled   = (float*)carve((size_t)NGRAPH * HID * 4);
    float* gcnt     = (float*)carve((size_t)NGRAPH * 4);
    int*   bsums    = (int*)carve(1024);
    int*   flag     = (int*)carve(256);

    const int nb = (N + 255) / 256;  // scan blocks (196 for N=50000)

    // graph preprocessing (once; shared by all 3 layers)
    detect_kernel<<<1, 256, 0, stream>>>((const int*)ei, flag);
    init_kernel<<<(N + 255) / 256, 256, 0, stream>>>(counts, pooled, gcnt, N);
    hist_kernel<<<(E + 255) / 256, 256, 0, stream>>>(ei, flag, counts, E, N);
    blocksum_kernel<<<nb, 256, 0, stream>>>(counts, bsums, N);
    scanb_kernel<<<1, 256, 0, stream>>>(bsums, nb);
    fill_kernel<<<nb, 256, 0, stream>>>(counts, bsums, rowstart, cursor, dinv, N);
    scatter_kernel<<<(E + 255) / 256, 256, 0, stream>>>(ei, flag, cursor, csr_src, E, N);

    int aggBlocks  = (N + 3) / 4;          // one wave per node, 4 waves/block
    int gemmBlocks = (N + 127) / 128;

    // layer 1: agg(x)->B, relu(B@W1+b1)->A
    agg_kernel<<<aggBlocks, 256, 0, stream>>>(x, rowstart, csr_src, dinv, bufB, N);
    gemm_bias_relu<<<gemmBlocks, 256, 0, stream>>>(bufB, W1, b1, bufA, N);
    // layer 2
    agg_kernel<<<aggBlocks, 256, 0, stream>>>(bufA, rowstart, csr_src, dinv, bufB, N);
    gemm_bias_relu<<<gemmBlocks, 256, 0, stream>>>(bufB, W2, b2, bufA, N);
    // layer 3
    agg_kernel<<<aggBlocks, 256, 0, stream>>>(bufA, rowstart, csr_src, dinv, bufB, N);
    gemm_bias_relu<<<gemmBlocks, 256, 0, stream>>>(bufB, W3, b3, bufA, N);

    // mean pool + final linear
    int poolWaves = (N + POOL_CHUNK - 1) / POOL_CHUNK;
    int poolBlocks = (poolWaves + 3) / 4;
    pool_kernel<<<poolBlocks, 256, 0, stream>>>(bufA, bat, flag, pooled, gcnt, N);
    final_kernel<<<5, 128, 0, stream>>>(pooled, gcnt, Wl, bl, out);
}

// Round 7
// 304.009 us; speedup vs baseline: 1.2008x; 1.1683x over previous
//
#include <hip/hip_runtime.h>
#include <hip/hip_bf16.h>
#include <hip/hip_fp16.h>

// ---------------------------------------------------------------------------
// GCN graph classifier: 3x GCNConv(128->128) + ReLU, mean-pool(64), linear(10)
// Strategy:
//   * Build CSR (by dst) once per call (graph identical across layers)
//   * Per layer: agg = A_norm * x  (pull-based gather, wave per node),
//                x' = relu(agg @ W + b)  (fp32 tiled GEMM, vector ALU)
//   * R6: GATHER SOURCE IS FP16 (256B rows, was 512B). agg accumulates fp32;
//     GEMM A-input fp32; layers 1-2 GEMM write fp16 h directly; layer 3 fp32
//     for pooling. Rationale: agg hit a ~3 TB/s byte ceiling on the L2-miss
//     path (R4 x8-unroll null + Little's-law -> byte-bound, not MLP-bound).
//   * Pool: batch sorted -> wave/16-node chunk (R1: was 2% occ, 152us)
//   * Scan: 3-kernel parallel scan (R2: single-block was 137us @0.14% occ)
//   * Agg: edge loop unrolled x8 (R3: MLP 1->4 = 72->48us)
//   * Scatter: stores ONLY csr_src (R5: halved random write-allocate traffic)
//   * Final: (sums @ Wlin)/cnt + blin  -> out[64][10]
// ---------------------------------------------------------------------------

#define HID 128
#define NGRAPH 64

__device__ __forceinline__ int idx_at(const void* p, long long i, int f64) {
    if (f64) return (int)((const long long*)p)[i];
    return ((const int*)p)[i];
}

// Detect whether index arrays are int64: sample odd 32-bit words of edge_index;
// for little-endian int64 with values < 2^31 they are all zero.
__global__ void detect_kernel(const int* __restrict__ ei, int* __restrict__ flag) {
    __shared__ int cnt;
    if (threadIdx.x == 0) cnt = 0;
    __syncthreads();
    int z = 0;
    for (int i = threadIdx.x; i < 2048; i += 256)
        if (ei[2 * i + 1] == 0) z++;
    atomicAdd(&cnt, z);
    __syncthreads();
    if (threadIdx.x == 0) *flag = (cnt > 1024) ? 1 : 0;
}

__global__ void init_kernel(int* __restrict__ counts, float* __restrict__ pooled,
                            float* __restrict__ gcnt, int N) {
    int i = blockIdx.x * blockDim.x + threadIdx.x;
    if (i < N) counts[i] = 0;
    if (i < NGRAPH * HID) pooled[i] = 0.f;
    if (i < NGRAPH) gcnt[i] = 0.f;
}

__global__ void hist_kernel(const void* __restrict__ ei, const int* __restrict__ flag,
                            int* __restrict__ counts, int E, int N) {
    int e = blockIdx.x * blockDim.x + threadIdx.x;
    if (e >= E) return;
    int f64 = *flag;
    int d = idx_at(ei, (long long)E + e, f64);
    if ((unsigned)d < (unsigned)N) atomicAdd(&counts[d], 1);
}

// fp32 -> fp16 copy (layer-1 gather source)
__global__ __launch_bounds__(256) void tohalf_kernel(const float* __restrict__ in,
                                                     __half2* __restrict__ out, int n2) {
    int i = blockIdx.x * blockDim.x + threadIdx.x;
    if (i >= n2) return;
    float2 v = ((const float2*)in)[i];
    out[i] = __floats2half2_rn(v.x, v.y);
}

__device__ __forceinline__ int wave_incl_scan(int v, int lane) {
#pragma unroll
    for (int off = 1; off < 64; off <<= 1) {
        int u = __shfl_up(v, off);
        if (lane >= off) v += u;
    }
    return v;
}

// ---- 3-kernel parallel exclusive scan over counts[N] (R2) ----
__global__ __launch_bounds__(256) void blocksum_kernel(const int* __restrict__ counts,
                                                       int* __restrict__ bsums, int N) {
    int i = blockIdx.x * 256 + threadIdx.x;
    int v = (i < N) ? counts[i] : 0;
    int lane = threadIdx.x & 63, w = threadIdx.x >> 6;
#pragma unroll
    for (int off = 32; off > 0; off >>= 1) v += __shfl_down(v, off);
    __shared__ int ws[4];
    if (lane == 0) ws[w] = v;
    __syncthreads();
    if (threadIdx.x == 0) bsums[blockIdx.x] = ws[0] + ws[1] + ws[2] + ws[3];
}

__global__ __launch_bounds__(256) void scanb_kernel(int* __restrict__ bsums, int nb) {
    int t = threadIdx.x;
    int lane = t & 63, w = t >> 6;
    int v = (t < nb) ? bsums[t] : 0;
    int iv = wave_incl_scan(v, lane);
    __shared__ int wsum[4];
    if (lane == 63) wsum[w] = iv;
    __syncthreads();
    int add = 0;
    for (int k = 0; k < w; ++k) add += wsum[k];
    if (t < nb) bsums[t] = iv - v + add;  // exclusive
}

__global__ __launch_bounds__(256) void fill_kernel(const int* __restrict__ counts,
                                                   const int* __restrict__ bsums,
                                                   int* __restrict__ rowstart,
                                                   int* __restrict__ cursor,
                                                   float* __restrict__ dinv, int N) {
    int i = blockIdx.x * 256 + threadIdx.x;
    int c = (i < N) ? counts[i] : 0;
    int lane = threadIdx.x & 63, w = threadIdx.x >> 6;
    int iv = wave_incl_scan(c, lane);
    __shared__ int wsum[4];
    if (lane == 63) wsum[w] = iv;
    __syncthreads();
    int add = bsums[blockIdx.x];
    for (int k = 0; k < w; ++k) add += wsum[k];
    int excl = iv - c + add;
    if (i < N) {
        rowstart[i] = excl;
        cursor[i] = excl;
        dinv[i] = rsqrtf((float)(c + 1));
        if (i == N - 1) rowstart[N] = excl + c;
    }
}

// R5: stores ONLY csr_src (norm recomputed in agg)
__global__ void scatter_kernel(const void* __restrict__ ei, const int* __restrict__ flag,
                               int* __restrict__ cursor,
                               int* __restrict__ csr_src, int E, int N) {
    int e = blockIdx.x * blockDim.x + threadIdx.x;
    if (e >= E) return;
    int f64 = *flag;
    int s = idx_at(ei, e, f64);
    int d = idx_at(ei, (long long)E + e, f64);
    if ((unsigned)s >= (unsigned)N || (unsigned)d >= (unsigned)N) return;
    int pos = atomicAdd(&cursor[d], 1);
    csr_src[pos] = s;
}

// out[i] = dinv[i]^2 * x[i] + sum_e (dinv[s]*dinv[i]) * x[s]
// Wave per node; gather source fp16 (half2/lane = 256B rows, R6); accumulate
// fp32; x8 MLP batching (R3).
__global__ __launch_bounds__(256) void agg_kernel(const __half2* __restrict__ xh,
                                                  const int* __restrict__ rowstart,
                                                  const int* __restrict__ csr_src,
                                                  const float* __restrict__ dinv,
                                                  float* __restrict__ out, int N) {
    int wid = (blockIdx.x * blockDim.x + threadIdx.x) >> 6;
    int lane = threadIdx.x & 63;
    if (wid >= N) return;
    float di = dinv[wid];
    float w0 = di * di;
    float2 xs = __half22float2(xh[(size_t)wid * 64 + lane]);
    float accx = w0 * xs.x, accy = w0 * xs.y;
    float bccx = 0.f, bccy = 0.f;
    int e0 = rowstart[wid], e1 = rowstart[wid + 1];
    int e = e0;
    for (; e + 8 <= e1; e += 8) {
        int s[8]; float ds[8]; __half2 v[8];
#pragma unroll
        for (int u = 0; u < 8; ++u) s[u] = csr_src[e + u];
#pragma unroll
        for (int u = 0; u < 8; ++u) ds[u] = dinv[s[u]];
#pragma unroll
        for (int u = 0; u < 8; ++u) v[u] = xh[(size_t)s[u] * 64 + lane];
#pragma unroll
        for (int u = 0; u < 8; u += 2) {
            float wa = ds[u] * di, wb = ds[u + 1] * di;
            float2 f0 = __half22float2(v[u]);
            float2 f1 = __half22float2(v[u + 1]);
            accx = fmaf(wa, f0.x, accx);
            accy = fmaf(wa, f0.y, accy);
            bccx = fmaf(wb, f1.x, bccx);
            bccy = fmaf(wb, f1.y, bccy);
        }
    }
    for (; e + 4 <= e1; e += 4) {
        int s[4]; float ds[4]; __half2 v[4];
#pragma unroll
        for (int u = 0; u < 4; ++u) s[u] = csr_src[e + u];
#pragma unroll
        for (int u = 0; u < 4; ++u) ds[u] = dinv[s[u]];
#pragma unroll
        for (int u = 0; u < 4; ++u) v[u] = xh[(size_t)s[u] * 64 + lane];
#pragma unroll
        for (int u = 0; u < 4; u += 2) {
            float wa = ds[u] * di, wb = ds[u + 1] * di;
            float2 f0 = __half22float2(v[u]);
            float2 f1 = __half22float2(v[u + 1]);
            accx = fmaf(wa, f0.x, accx);
            accy = fmaf(wa, f0.y, accy);
            bccx = fmaf(wb, f1.x, bccx);
            bccy = fmaf(wb, f1.y, bccy);
        }
    }
    for (; e < e1; ++e) {
        int s = csr_src[e];
        float w = dinv[s] * di;
        float2 f = __half22float2(xh[(size_t)s * 64 + lane]);
        accx = fmaf(w, f.x, accx);
        accy = fmaf(w, f.y, accy);
    }
    float2 r; r.x = accx + bccx; r.y = accy + bccy;
    ((float2*)out)[(size_t)wid * 64 + lane] = r;
}

// O = relu(A @ W + bias), A:[M][128] fp32, W:[128][128]. 128x128 tile, 8x8
// microtile. OUT_HALF: write fp16 (gather source for next layer, R6) else fp32.
#define LP 132
template <bool OUT_HALF>
__global__ __launch_bounds__(256) void gemm_bias_relu(const float* __restrict__ A,
                                                      const float* __restrict__ W,
                                                      const float* __restrict__ bias,
                                                      float* __restrict__ O32,
                                                      __half2* __restrict__ O16, int M) {
    __shared__ float As[32][LP];  // As[k][r] (transposed)
    __shared__ float Ws[32][LP];  // Ws[k][c]
    int t = threadIdx.x;
    int tx = t & 15, ty = t >> 4;
    int r0 = ty * 8, c0 = tx * 8;
    int blockRow = blockIdx.x * 128;
    float acc[8][8];
#pragma unroll
    for (int i = 0; i < 8; i++)
#pragma unroll
        for (int j = 0; j < 8; j++) acc[i][j] = 0.f;

    for (int k0 = 0; k0 < 128; k0 += 32) {
        __syncthreads();
#pragma unroll
        for (int q = 0; q < 4; ++q) {
            int id = t + 256 * q;
            int row = id >> 3, kk4 = id & 7;
            int grow = blockRow + row;
            float4 v = make_float4(0.f, 0.f, 0.f, 0.f);
            if (grow < M) v = *(const float4*)&A[(size_t)grow * 128 + k0 + kk4 * 4];
            As[kk4 * 4 + 0][row] = v.x;
            As[kk4 * 4 + 1][row] = v.y;
            As[kk4 * 4 + 2][row] = v.z;
            As[kk4 * 4 + 3][row] = v.w;
        }
#pragma unroll
        for (int q = 0; q < 4; ++q) {
            int id = t + 256 * q;
            int krow = id >> 5, c4 = id & 31;
            float4 v = *(const float4*)&W[(size_t)(k0 + krow) * 128 + c4 * 4];
            *(float4*)&Ws[krow][c4 * 4] = v;
        }
        __syncthreads();
#pragma unroll 4
        for (int k = 0; k < 32; ++k) {
            float4 a0 = *(const float4*)&As[k][r0];
            float4 a1 = *(const float4*)&As[k][r0 + 4];
            float4 b0 = *(const float4*)&Ws[k][c0];
            float4 b1 = *(const float4*)&Ws[k][c0 + 4];
            float a[8] = {a0.x, a0.y, a0.z, a0.w, a1.x, a1.y, a1.z, a1.w};
            float b[8] = {b0.x, b0.y, b0.z, b0.w, b1.x, b1.y, b1.z, b1.w};
#pragma unroll
            for (int i = 0; i < 8; i++)
#pragma unroll
                for (int j = 0; j < 8; j++) acc[i][j] = fmaf(a[i], b[j], acc[i][j]);
        }
    }
#pragma unroll
    for (int i = 0; i < 8; i++) {
        int gr = blockRow + r0 + i;
        if (gr >= M) break;
#pragma unroll
        for (int j = 0; j < 8; j += 4) {
            float4 o;
            o.x = fmaxf(acc[i][j + 0] + bias[c0 + j + 0], 0.f);
            o.y = fmaxf(acc[i][j + 1] + bias[c0 + j + 1], 0.f);
            o.z = fmaxf(acc[i][j + 2] + bias[c0 + j + 2], 0.f);
            o.w = fmaxf(acc[i][j + 3] + bias[c0 + j + 3], 0.f);
            if (OUT_HALF) {
                __half2 p0 = __floats2half2_rn(o.x, o.y);
                __half2 p1 = __floats2half2_rn(o.z, o.w);
                size_t base = (size_t)gr * 64 + ((c0 + j) >> 1);
                O16[base] = p0;
                O16[base + 1] = p1;
            } else {
                *(float4*)&O32[(size_t)gr * 128 + c0 + j] = o;
            }
        }
    }
}

// batch is sorted: one WAVE per 16-node chunk, float2/lane (128 features),
// atomic flush at graph boundaries (R1).
#define POOL_CHUNK 16
__global__ __launch_bounds__(256) void pool_kernel(const float* __restrict__ h,
                                                   const void* __restrict__ batch,
                                                   const int* __restrict__ flag,
                                                   float* __restrict__ pooled,
                                                   float* __restrict__ gcnt, int N) {
    int wid = (blockIdx.x * blockDim.x + threadIdx.x) >> 6;
    int lane = threadIdx.x & 63;
    int n0 = wid * POOL_CHUNK;
    if (n0 >= N) return;
    int n1 = n0 + POOL_CHUNK; if (n1 > N) n1 = N;
    int f64 = *flag;
    const float2* h2 = (const float2*)h;
    int g = idx_at(batch, n0, f64);
    float ax = 0.f, ay = 0.f;
    int cnt = 0;
    for (int n = n0; n < n1; ++n) {
        int gn = idx_at(batch, n, f64);
        if (gn != g) {
            if ((unsigned)g < (unsigned)NGRAPH) {
                atomicAdd(&pooled[g * HID + 2 * lane], ax);
                atomicAdd(&pooled[g * HID + 2 * lane + 1], ay);
                if (lane == 0) atomicAdd(&gcnt[g], (float)cnt);
            }
            ax = ay = 0.f; cnt = 0; g = gn;
        }
        float2 v = h2[(size_t)n * 64 + lane];
        ax += v.x; ay += v.y; cnt++;
    }
    if ((unsigned)g < (unsigned)NGRAPH) {
        atomicAdd(&pooled[g * HID + 2 * lane], ax);
        atomicAdd(&pooled[g * HID + 2 * lane + 1], ay);
        if (lane == 0) atomicAdd(&gcnt[g], (float)cnt);
    }
}

__global__ __launch_bounds__(128) void final_kernel(const float* __restrict__ pooled,
                                                    const float* __restrict__ gcnt,
                                                    const float* __restrict__ Wl,
                                                    const float* __restrict__ bl,
                                                    float* __restrict__ out) {
    int o = blockIdx.x * blockDim.x + threadIdx.x;
    if (o >= NGRAPH * 10) return;
    int g = o / 10, c = o % 10;
    float inv = 1.0f / fmaxf(gcnt[g], 1.0f);
    float acc = 0.f;
    for (int k = 0; k < HID; ++k)
        acc = fmaf(pooled[g * HID + k], Wl[k * 10 + c], acc);
    out[o] = acc * inv + bl[c];
}

extern "C" void kernel_launch(void* const* d_in, const int* in_sizes, int n_in,
                              void* d_out, int out_size, void* d_ws, size_t ws_size,
                              hipStream_t stream) {
    const float* x   = (const float*)d_in[0];
    const void* ei   = d_in[1];
    const void* bat  = d_in[2];
    const float* W1  = (const float*)d_in[3];
    const float* b1  = (const float*)d_in[4];
    const float* W2  = (const float*)d_in[5];
    const float* b2  = (const float*)d_in[6];
    const float* W3  = (const float*)d_in[7];
    const float* b3  = (const float*)d_in[8];
    const float* Wl  = (const float*)d_in[9];
    const float* bl  = (const float*)d_in[10];
    float* out = (float*)d_out;

    const int N = in_sizes[0] / HID;   // 50000
    const int E = in_sizes[1] / 2;     // 600000

    char* w = (char*)d_ws;
    size_t off = 0;
    auto carve = [&](size_t bytes) -> void* {
        void* p = w + off;
        off = (off + bytes + 255) & ~(size_t)255;
        return p;
    };
    float*   bufA     = (float*)carve((size_t)N * HID * 4);   // fp32 agg out + L3 gemm out
    float*   bufB     = (float*)carve((size_t)N * HID * 4);
    __half2* xh       = (__half2*)carve((size_t)N * HID * 2); // fp16 x copy
    __half2* h16      = (__half2*)carve((size_t)N * HID * 2); // fp16 h (layers 1-2)
    int*     counts   = (int*)carve((size_t)N * 4);
    int*     rowstart = (int*)carve((size_t)(N + 1) * 4);
    int*     cursor   = (int*)carve((size_t)N * 4);
    float*   dinv     = (float*)carve((size_t)N * 4);
    int*     csr_src  = (int*)carve((size_t)E * 4);
    float*   pooled   = (float*)carve((size_t)NGRAPH * HID * 4);
    float*   gcnt     = (float*)carve((size_t)NGRAPH * 4);
    int*     bsums    = (int*)carve(1024);
    int*     flag     = (int*)carve(256);

    const int nb = (N + 255) / 256;

    // graph preprocessing (once; shared by all 3 layers)
    detect_kernel<<<1, 256, 0, stream>>>((const int*)ei, flag);
    init_kernel<<<(N + 255) / 256, 256, 0, stream>>>(counts, pooled, gcnt, N);
    hist_kernel<<<(E + 255) / 256, 256, 0, stream>>>(ei, flag, counts, E, N);
    blocksum_kernel<<<nb, 256, 0, stream>>>(counts, bsums, N);
    scanb_kernel<<<1, 256, 0, stream>>>(bsums, nb);
    fill_kernel<<<nb, 256, 0, stream>>>(counts, bsums, rowstart, cursor, dinv, N);
    scatter_kernel<<<(E + 255) / 256, 256, 0, stream>>>(ei, flag, cursor, csr_src, E, N);

    const int n2 = N * HID / 2;
    tohalf_kernel<<<(n2 + 255) / 256, 256, 0, stream>>>(x, xh, n2);

    int aggBlocks  = (N + 3) / 4;          // one wave per node, 4 waves/block
    int gemmBlocks = (N + 127) / 128;

    // layer 1: agg(xh)->B, relu(B@W1+b1)->h16 (fp16)
    agg_kernel<<<aggBlocks, 256, 0, stream>>>(xh, rowstart, csr_src, dinv, bufB, N);
    gemm_bias_relu<true><<<gemmBlocks, 256, 0, stream>>>(bufB, W1, b1, nullptr, h16, N);
    // layer 2: agg(h16)->B, relu(B@W2+b2)->h16 (sequential kernels -> safe reuse)
    agg_kernel<<<aggBlocks, 256, 0, stream>>>(h16, rowstart, csr_src, dinv, bufB, N);
    gemm_bias_relu<true><<<gemmBlocks, 256, 0, stream>>>(bufB, W2, b2, nullptr, h16, N);
    // layer 3: agg(h16)->B, relu(B@W3+b3)->bufA (fp32 for pooling)
    agg_kernel<<<aggBlocks, 256, 0, stream>>>(h16, rowstart, csr_src, dinv, bufB, N);
    gemm_bias_relu<false><<<gemmBlocks, 256, 0, stream>>>(bufB, W3, b3, bufA, nullptr, N);

    // mean pool + final linear
    int poolWaves = (N + POOL_CHUNK - 1) / POOL_CHUNK;
    int poolBlocks = (poolWaves + 3) / 4;
    pool_kernel<<<poolBlocks, 256, 0, stream>>>(bufA, bat, flag, pooled, gcnt, N);
    final_kernel<<<5, 128, 0, stream>>>(pooled, gcnt, Wl, bl, out);
}

// Round 8
// 256.443 us; speedup vs baseline: 1.4235x; 1.1855x over previous
//
#include <hip/hip_runtime.h>
#include <hip/hip_bf16.h>
#include <hip/hip_fp16.h>

// ---------------------------------------------------------------------------
// GCN graph classifier: 3x GCNConv(128->128) + ReLU, mean-pool(64), linear(10)
// Strategy:
//   * Build CSR (by dst) once per call (graph identical across layers)
//   * Per layer: agg = A_norm * x  (pull-based fp16 gather, wave per node,
//     fp32 accumulate, fp16 out), then h = relu(agg @ W + b) via fp16 MFMA
//     (R7: vector-ALU fp32 GEMM was 40us at 12% occupancy / 27% VALUBusy;
//     MFMA GEMM is LDS-free, 782 blocks, W pre-packed into fragment order)
//   * R6: gather source fp16 (256B rows) -- agg was byte-bound at ~3 TB/s on
//     the L2-miss path
//   * Pool: batch sorted -> wave/16-node chunk (R1: was 2% occ, 152us)
//   * Scan: 3-kernel parallel scan (R2: single-block was 137us @0.14% occ)
//   * Agg: edge loop unrolled x8 (R3: MLP 1->4 = 72->48us)
//   * Scatter: stores ONLY csr_src (R5: halved random write-allocate traffic)
//   * Final: (sums @ Wlin)/cnt + blin  -> out[64][10]
// MFMA layout note: A-frag and B-frag use the SAME (hi,reg)->k map, so any
// hardware k-permutation cancels (dot products are k-permutation-invariant).
// C/D map col=lane&15,row=(lane>>4)*4+reg is HW-verified (learn_hip m89).
// ---------------------------------------------------------------------------

#define HID 128
#define NGRAPH 64

typedef _Float16 half8v __attribute__((ext_vector_type(8)));
typedef float floatx4 __attribute__((ext_vector_type(4)));

__device__ __forceinline__ int idx_at(const void* p, long long i, int f64) {
    if (f64) return (int)((const long long*)p)[i];
    return ((const int*)p)[i];
}

// Detect whether index arrays are int64: sample odd 32-bit words of edge_index;
// for little-endian int64 with values < 2^31 they are all zero.
__global__ void detect_kernel(const int* __restrict__ ei, int* __restrict__ flag) {
    __shared__ int cnt;
    if (threadIdx.x == 0) cnt = 0;
    __syncthreads();
    int z = 0;
    for (int i = threadIdx.x; i < 2048; i += 256)
        if (ei[2 * i + 1] == 0) z++;
    atomicAdd(&cnt, z);
    __syncthreads();
    if (threadIdx.x == 0) *flag = (cnt > 1024) ? 1 : 0;
}

__global__ void init_kernel(int* __restrict__ counts, float* __restrict__ pooled,
                            float* __restrict__ gcnt, int N) {
    int i = blockIdx.x * blockDim.x + threadIdx.x;
    if (i < N) counts[i] = 0;
    if (i < NGRAPH * HID) pooled[i] = 0.f;
    if (i < NGRAPH) gcnt[i] = 0.f;
}

__global__ void hist_kernel(const void* __restrict__ ei, const int* __restrict__ flag,
                            int* __restrict__ counts, int E, int N) {
    int e = blockIdx.x * blockDim.x + threadIdx.x;
    if (e >= E) return;
    int f64 = *flag;
    int d = idx_at(ei, (long long)E + e, f64);
    if ((unsigned)d < (unsigned)N) atomicAdd(&counts[d], 1);
}

// fp32 -> fp16 copy (layer-1 gather source)
__global__ __launch_bounds__(256) void tohalf_kernel(const float* __restrict__ in,
                                                     __half2* __restrict__ out, int n2) {
    int i = blockIdx.x * blockDim.x + threadIdx.x;
    if (i >= n2) return;
    float2 v = ((const float2*)in)[i];
    out[i] = __floats2half2_rn(v.x, v.y);
}

// Pack W[128][128] fp32 into fragment-ordered fp16: wf[(kblk*8+nt)*64+lane] =
// { W[kblk*32+(lane>>4)*8+j][nt*16+(lane&15)] : j=0..7 }.
__global__ __launch_bounds__(256) void wfrag_kernel(const float* __restrict__ W,
                                                    half8v* __restrict__ wf) {
    int t = blockIdx.x * 256 + threadIdx.x;
    if (t >= 2048) return;
    int lane = t & 63;
    int nt = (t >> 6) & 7;
    int kblk = t >> 9;
    int n = nt * 16 + (lane & 15);
    int kbase = kblk * 32 + (lane >> 4) * 8;
    half8v v;
#pragma unroll
    for (int j = 0; j < 8; ++j) v[j] = (_Float16)W[(size_t)(kbase + j) * 128 + n];
    wf[t] = v;
}

__device__ __forceinline__ int wave_incl_scan(int v, int lane) {
#pragma unroll
    for (int off = 1; off < 64; off <<= 1) {
        int u = __shfl_up(v, off);
        if (lane >= off) v += u;
    }
    return v;
}

// ---- 3-kernel parallel exclusive scan over counts[N] (R2) ----
__global__ __launch_bounds__(256) void blocksum_kernel(const int* __restrict__ counts,
                                                       int* __restrict__ bsums, int N) {
    int i = blockIdx.x * 256 + threadIdx.x;
    int v = (i < N) ? counts[i] : 0;
    int lane = threadIdx.x & 63, w = threadIdx.x >> 6;
#pragma unroll
    for (int off = 32; off > 0; off >>= 1) v += __shfl_down(v, off);
    __shared__ int ws[4];
    if (lane == 0) ws[w] = v;
    __syncthreads();
    if (threadIdx.x == 0) bsums[blockIdx.x] = ws[0] + ws[1] + ws[2] + ws[3];
}

__global__ __launch_bounds__(256) void scanb_kernel(int* __restrict__ bsums, int nb) {
    int t = threadIdx.x;
    int lane = t & 63, w = t >> 6;
    int v = (t < nb) ? bsums[t] : 0;
    int iv = wave_incl_scan(v, lane);
    __shared__ int wsum[4];
    if (lane == 63) wsum[w] = iv;
    __syncthreads();
    int add = 0;
    for (int k = 0; k < w; ++k) add += wsum[k];
    if (t < nb) bsums[t] = iv - v + add;  // exclusive
}

__global__ __launch_bounds__(256) void fill_kernel(const int* __restrict__ counts,
                                                   const int* __restrict__ bsums,
                                                   int* __restrict__ rowstart,
                                                   int* __restrict__ cursor,
                                                   float* __restrict__ dinv, int N) {
    int i = blockIdx.x * 256 + threadIdx.x;
    int c = (i < N) ? counts[i] : 0;
    int lane = threadIdx.x & 63, w = threadIdx.x >> 6;
    int iv = wave_incl_scan(c, lane);
    __shared__ int wsum[4];
    if (lane == 63) wsum[w] = iv;
    __syncthreads();
    int add = bsums[blockIdx.x];
    for (int k = 0; k < w; ++k) add += wsum[k];
    int excl = iv - c + add;
    if (i < N) {
        rowstart[i] = excl;
        cursor[i] = excl;
        dinv[i] = rsqrtf((float)(c + 1));
        if (i == N - 1) rowstart[N] = excl + c;
    }
}

// R5: stores ONLY csr_src (norm recomputed in agg)
__global__ void scatter_kernel(const void* __restrict__ ei, const int* __restrict__ flag,
                               int* __restrict__ cursor,
                               int* __restrict__ csr_src, int E, int N) {
    int e = blockIdx.x * blockDim.x + threadIdx.x;
    if (e >= E) return;
    int f64 = *flag;
    int s = idx_at(ei, e, f64);
    int d = idx_at(ei, (long long)E + e, f64);
    if ((unsigned)s >= (unsigned)N || (unsigned)d >= (unsigned)N) return;
    int pos = atomicAdd(&cursor[d], 1);
    csr_src[pos] = s;
}

// out[i] = dinv[i]^2 * x[i] + sum_e (dinv[s]*dinv[i]) * x[s]
// Wave per node; fp16 gather (256B rows), fp32 accumulate, fp16 out (R7:
// MFMA GEMM consumes fp16 A). x8 MLP batching (R3).
__global__ __launch_bounds__(256) void agg_kernel(const __half2* __restrict__ xh,
                                                  const int* __restrict__ rowstart,
                                                  const int* __restrict__ csr_src,
                                                  const float* __restrict__ dinv,
                                                  __half2* __restrict__ out, int N) {
    int wid = (blockIdx.x * blockDim.x + threadIdx.x) >> 6;
    int lane = threadIdx.x & 63;
    if (wid >= N) return;
    float di = dinv[wid];
    float w0 = di * di;
    float2 xs = __half22float2(xh[(size_t)wid * 64 + lane]);
    float accx = w0 * xs.x, accy = w0 * xs.y;
    float bccx = 0.f, bccy = 0.f;
    int e0 = rowstart[wid], e1 = rowstart[wid + 1];
    int e = e0;
    for (; e + 8 <= e1; e += 8) {
        int s[8]; float ds[8]; __half2 v[8];
#pragma unroll
        for (int u = 0; u < 8; ++u) s[u] = csr_src[e + u];
#pragma unroll
        for (int u = 0; u < 8; ++u) ds[u] = dinv[s[u]];
#pragma unroll
        for (int u = 0; u < 8; ++u) v[u] = xh[(size_t)s[u] * 64 + lane];
#pragma unroll
        for (int u = 0; u < 8; u += 2) {
            float wa = ds[u] * di, wb = ds[u + 1] * di;
            float2 f0 = __half22float2(v[u]);
            float2 f1 = __half22float2(v[u + 1]);
            accx = fmaf(wa, f0.x, accx);
            accy = fmaf(wa, f0.y, accy);
            bccx = fmaf(wb, f1.x, bccx);
            bccy = fmaf(wb, f1.y, bccy);
        }
    }
    for (; e + 4 <= e1; e += 4) {
        int s[4]; float ds[4]; __half2 v[4];
#pragma unroll
        for (int u = 0; u < 4; ++u) s[u] = csr_src[e + u];
#pragma unroll
        for (int u = 0; u < 4; ++u) ds[u] = dinv[s[u]];
#pragma unroll
        for (int u = 0; u < 4; ++u) v[u] = xh[(size_t)s[u] * 64 + lane];
#pragma unroll
        for (int u = 0; u < 4; u += 2) {
            float wa = ds[u] * di, wb = ds[u + 1] * di;
            float2 f0 = __half22float2(v[u]);
            float2 f1 = __half22float2(v[u + 1]);
            accx = fmaf(wa, f0.x, accx);
            accy = fmaf(wa, f0.y, accy);
            bccx = fmaf(wb, f1.x, bccx);
            bccy = fmaf(wb, f1.y, bccy);
        }
    }
    for (; e < e1; ++e) {
        int s = csr_src[e];
        float w = dinv[s] * di;
        float2 f = __half22float2(xh[(size_t)s * 64 + lane]);
        accx = fmaf(w, f.x, accx);
        accy = fmaf(w, f.y, accy);
    }
    out[(size_t)wid * 64 + lane] = __floats2half2_rn(accx + bccx, accy + bccy);
}

// h = relu(A @ W + b) via v_mfma_f32_16x16x32_f16. A:[M][128] fp16, W pre-
// packed fragments (L2-resident 32KB). No LDS, no barriers. Wave owns 16 rows
// x 128 cols (8 n-tiles x 4 k-blocks = 32 MFMAs). Block = 4 waves = 64 rows.
template <bool OUT_HALF>
__global__ __launch_bounds__(256) void gemm_mfma(const __half2* __restrict__ A16,
                                                 const half8v* __restrict__ wf,
                                                 const float* __restrict__ bias,
                                                 float* __restrict__ O32,
                                                 __half2* __restrict__ O16, int M) {
    int wid = threadIdx.x >> 6, lane = threadIdx.x & 63;
    int rowTile = blockIdx.x * 64 + wid * 16;
    int hi = lane >> 4;
    int arow = rowTile + (lane & 15);
    if (arow >= M) arow = M - 1;  // clamp; outputs guarded below
    const half8v* Arow = (const half8v*)((const _Float16*)A16 + (size_t)arow * 128);

    floatx4 acc[8];
#pragma unroll
    for (int nt = 0; nt < 8; ++nt) acc[nt] = (floatx4){0.f, 0.f, 0.f, 0.f};

#pragma unroll
    for (int kb = 0; kb < 4; ++kb) {
        half8v a = Arow[kb * 4 + hi];
#pragma unroll
        for (int nt = 0; nt < 8; ++nt) {
            half8v w = wf[(kb * 8 + nt) * 64 + lane];
            acc[nt] = __builtin_amdgcn_mfma_f32_16x16x32_f16(a, w, acc[nt], 0, 0, 0);
        }
    }

    // C/D: col = lane&15, row = (lane>>4)*4 + reg   [HW-verified]
    int ocol_lo = lane & 15;
    int orow0 = rowTile + hi * 4;
#pragma unroll
    for (int nt = 0; nt < 8; ++nt) {
        int col = nt * 16 + ocol_lo;
        float b = bias[col];
#pragma unroll
        for (int r = 0; r < 4; ++r) {
            int orow = orow0 + r;
            if (orow < M) {
                float v = fmaxf(acc[nt][r] + b, 0.f);
                if (OUT_HALF)
                    ((_Float16*)O16)[(size_t)orow * 128 + col] = (_Float16)v;
                else
                    O32[(size_t)orow * 128 + col] = v;
            }
        }
    }
}

// batch is sorted: one WAVE per 16-node chunk, float2/lane (128 features),
// atomic flush at graph boundaries (R1).
#define POOL_CHUNK 16
__global__ __launch_bounds__(256) void pool_kernel(const float* __restrict__ h,
                                                   const void* __restrict__ batch,
                                                   const int* __restrict__ flag,
                                                   float* __restrict__ pooled,
                                                   float* __restrict__ gcnt, int N) {
    int wid = (blockIdx.x * blockDim.x + threadIdx.x) >> 6;
    int lane = threadIdx.x & 63;
    int n0 = wid * POOL_CHUNK;
    if (n0 >= N) return;
    int n1 = n0 + POOL_CHUNK; if (n1 > N) n1 = N;
    int f64 = *flag;
    const float2* h2 = (const float2*)h;
    int g = idx_at(batch, n0, f64);
    float ax = 0.f, ay = 0.f;
    int cnt = 0;
    for (int n = n0; n < n1; ++n) {
        int gn = idx_at(batch, n, f64);
        if (gn != g) {
            if ((unsigned)g < (unsigned)NGRAPH) {
                atomicAdd(&pooled[g * HID + 2 * lane], ax);
                atomicAdd(&pooled[g * HID + 2 * lane + 1], ay);
                if (lane == 0) atomicAdd(&gcnt[g], (float)cnt);
            }
            ax = ay = 0.f; cnt = 0; g = gn;
        }
        float2 v = h2[(size_t)n * 64 + lane];
        ax += v.x; ay += v.y; cnt++;
    }
    if ((unsigned)g < (unsigned)NGRAPH) {
        atomicAdd(&pooled[g * HID + 2 * lane], ax);
        atomicAdd(&pooled[g * HID + 2 * lane + 1], ay);
        if (lane == 0) atomicAdd(&gcnt[g], (float)cnt);
    }
}

__global__ __launch_bounds__(128) void final_kernel(const float* __restrict__ pooled,
                                                    const float* __restrict__ gcnt,
                                                    const float* __restrict__ Wl,
                                                    const float* __restrict__ bl,
                                                    float* __restrict__ out) {
    int o = blockIdx.x * blockDim.x + threadIdx.x;
    if (o >= NGRAPH * 10) return;
    int g = o / 10, c = o % 10;
    float inv = 1.0f / fmaxf(gcnt[g], 1.0f);
    float acc = 0.f;
    for (int k = 0; k < HID; ++k)
        acc = fmaf(pooled[g * HID + k], Wl[k * 10 + c], acc);
    out[o] = acc * inv + bl[c];
}

extern "C" void kernel_launch(void* const* d_in, const int* in_sizes, int n_in,
                              void* d_out, int out_size, void* d_ws, size_t ws_size,
                              hipStream_t stream) {
    const float* x   = (const float*)d_in[0];
    const void* ei   = d_in[1];
    const void* bat  = d_in[2];
    const float* W1  = (const float*)d_in[3];
    const float* b1  = (const float*)d_in[4];
    const float* W2  = (const float*)d_in[5];
    const float* b2  = (const float*)d_in[6];
    const float* W3  = (const float*)d_in[7];
    const float* b3  = (const float*)d_in[8];
    const float* Wl  = (const float*)d_in[9];
    const float* bl  = (const float*)d_in[10];
    float* out = (float*)d_out;

    const int N = in_sizes[0] / HID;   // 50000
    const int E = in_sizes[1] / 2;     // 600000

    char* w = (char*)d_ws;
    size_t off = 0;
    auto carve = [&](size_t bytes) -> void* {
        void* p = w + off;
        off = (off + bytes + 255) & ~(size_t)255;
        return p;
    };
    float*   bufA     = (float*)carve((size_t)N * HID * 4);   // layer-3 out (fp32, pool src)
    __half2* aggB16   = (__half2*)carve((size_t)N * HID * 2); // agg out (fp16, GEMM A)
    __half2* xh       = (__half2*)carve((size_t)N * HID * 2); // fp16 x copy
    __half2* h16      = (__half2*)carve((size_t)N * HID * 2); // fp16 h (layers 1-2)
    int*     counts   = (int*)carve((size_t)N * 4);
    int*     rowstart = (int*)carve((size_t)(N + 1) * 4);
    int*     cursor   = (int*)carve((size_t)N * 4);
    float*   dinv     = (float*)carve((size_t)N * 4);
    int*     csr_src  = (int*)carve((size_t)E * 4);
    float*   pooled   = (float*)carve((size_t)NGRAPH * HID * 4);
    float*   gcnt     = (float*)carve((size_t)NGRAPH * 4);
    half8v*  wf1      = (half8v*)carve(2048 * 16);
    half8v*  wf2      = (half8v*)carve(2048 * 16);
    half8v*  wf3      = (half8v*)carve(2048 * 16);
    int*     bsums    = (int*)carve(1024);
    int*     flag     = (int*)carve(256);

    const int nb = (N + 255) / 256;

    // graph preprocessing (once; shared by all 3 layers)
    detect_kernel<<<1, 256, 0, stream>>>((const int*)ei, flag);
    init_kernel<<<(N + 255) / 256, 256, 0, stream>>>(counts, pooled, gcnt, N);
    hist_kernel<<<(E + 255) / 256, 256, 0, stream>>>(ei, flag, counts, E, N);
    blocksum_kernel<<<nb, 256, 0, stream>>>(counts, bsums, N);
    scanb_kernel<<<1, 256, 0, stream>>>(bsums, nb);
    fill_kernel<<<nb, 256, 0, stream>>>(counts, bsums, rowstart, cursor, dinv, N);
    scatter_kernel<<<(E + 255) / 256, 256, 0, stream>>>(ei, flag, cursor, csr_src, E, N);

    const int n2 = N * HID / 2;
    tohalf_kernel<<<(n2 + 255) / 256, 256, 0, stream>>>(x, xh, n2);
    wfrag_kernel<<<8, 256, 0, stream>>>(W1, wf1);
    wfrag_kernel<<<8, 256, 0, stream>>>(W2, wf2);
    wfrag_kernel<<<8, 256, 0, stream>>>(W3, wf3);

    int aggBlocks  = (N + 3) / 4;        // one wave per node, 4 waves/block
    int gemmBlocks = (N + 63) / 64;      // 64 rows/block (4 waves x 16 rows)

    // layer 1
    agg_kernel<<<aggBlocks, 256, 0, stream>>>(xh, rowstart, csr_src, dinv, aggB16, N);
    gemm_mfma<true><<<gemmBlocks, 256, 0, stream>>>(aggB16, wf1, b1, nullptr, h16, N);
    // layer 2
    agg_kernel<<<aggBlocks, 256, 0, stream>>>(h16, rowstart, csr_src, dinv, aggB16, N);
    gemm_mfma<true><<<gemmBlocks, 256, 0, stream>>>(aggB16, wf2, b2, nullptr, h16, N);
    // layer 3 (fp32 out for pooling)
    agg_kernel<<<aggBlocks, 256, 0, stream>>>(h16, rowstart, csr_src, dinv, aggB16, N);
    gemm_mfma<false><<<gemmBlocks, 256, 0, stream>>>(aggB16, wf3, b3, bufA, nullptr, N);

    // mean pool + final linear
    int poolWaves = (N + POOL_CHUNK - 1) / POOL_CHUNK;
    int poolBlocks = (poolWaves + 3) / 4;
    pool_kernel<<<poolBlocks, 256, 0, stream>>>(bufA, bat, flag, pooled, gcnt, N);
    final_kernel<<<5, 128, 0, stream>>>(pooled, gcnt, Wl, bl, out);
}